// Round 11
// baseline (274.835 us; speedup 1.0000x reference)
//
#include <hip/hip_runtime.h>

// GIN: 2x GINConv(eps=0, MLP 2-layer) + ReLU, then Linear(128->1).
// N=50000 nodes, E=800000 edges, IN=64, HID=128.
//
// Round 11: node ids fit in 16 bits (N=50000 < 65536) ->
// (a) edge list compacted once to ushort srcs16/dsts16 (3.2MB); the 8x
//     XCD-affine hist/fill sweeps now stream 2B ids (75% less traffic);
// (b) col[] stored as ushort (halves fill writes + gather col reads);
// (c) gather128 processes 4 neighbors/iter (more MLP vs ~200cy L2/L3 lat).

#define N_NODES 50000
#define IN_CH 64
#define HID 128
#define REGION 6250   // N/8 dst-nodes per XCD-affine region

typedef short short8 __attribute__((ext_vector_type(8)));
typedef float f32x4 __attribute__((ext_vector_type(4)));

__device__ __forceinline__ unsigned bf16_rne(float f) {
    unsigned u = __float_as_uint(f);
    return (u + 0x7FFFu + ((u >> 16) & 1u)) >> 16;
}
__device__ __forceinline__ float lo_f(unsigned u) { return __uint_as_float(u << 16); }
__device__ __forceinline__ float hi_f(unsigned u) { return __uint_as_float(u & 0xFFFF0000u); }

// ---------------- edge dtype detection (int64 vs int32) ----------------
__global__ void detect64_kernel(const int* __restrict__ ei32, int* __restrict__ flag) {
    int t = threadIdx.x;  // 256 threads
    int v = ei32[2 * t + 1];
    unsigned long long b = __ballot(v != 0);
    __shared__ unsigned long long r[4];
    if ((t & 63) == 0) r[t >> 6] = b;
    __syncthreads();
    if (t == 0) flag[0] = ((r[0] | r[1] | r[2] | r[3]) == 0ULL) ? 1 : 0;
}

__device__ __forceinline__ int load_idx(const void* ei, int is64, int pos) {
    if (is64) return (int)((const long long*)ei)[pos];
    return ((const int*)ei)[pos];
}

// ---------------- compact edge list to ushort ----------------
__global__ __launch_bounds__(256) void compact_kernel(
    const void* __restrict__ ei, const int* __restrict__ is64,
    ushort* __restrict__ srcs, ushort* __restrict__ dsts, int E)
{
    int i64 = *is64;
    for (int e = blockIdx.x * 256 + threadIdx.x; e < E; e += gridDim.x * 256) {
        srcs[e] = (ushort)load_idx(ei, i64, e);
        dsts[e] = (ushort)load_idx(ei, i64, E + e);
    }
}

// ---------------- CSR build, XCD-affine (bid%8 == dst region), ushort ids ----------------
__global__ __launch_bounds__(256) void hist8_kernel(
    const ushort* __restrict__ dsts, int* __restrict__ deg, int E, int nsub)
{
    int g   = blockIdx.x & 7;
    int sub = blockIdx.x >> 3;
    int lo = g * REGION, hi = lo + REGION;
    for (int e = sub * 256 + threadIdx.x; e < E; e += nsub * 256) {
        int d = dsts[e];
        if (d >= lo && d < hi) atomicAdd(&deg[d], 1);
    }
}

__global__ __launch_bounds__(256) void fill8_kernel(
    const ushort* __restrict__ srcs, const ushort* __restrict__ dsts,
    int* __restrict__ cursor, ushort* __restrict__ col, int E, int nsub)
{
    int g   = blockIdx.x & 7;
    int sub = blockIdx.x >> 3;
    int lo = g * REGION, hi = lo + REGION;
    for (int e = sub * 256 + threadIdx.x; e < E; e += nsub * 256) {
        int d = dsts[e];
        if (d >= lo && d < hi) {
            int pos = atomicAdd(&cursor[d], 1);
            col[pos] = srcs[e];
        }
    }
}

__device__ __forceinline__ int wave_incl_scan(int v, int lane) {
    #pragma unroll
    for (int off = 1; off < 64; off <<= 1) {
        int u = __shfl_up(v, off);
        if (lane >= off) v += u;
    }
    return v;
}

__global__ __launch_bounds__(256) void scan1_kernel(
    const int* __restrict__ deg, int* __restrict__ incl,
    int* __restrict__ bsum, int N)
{
    int i = blockIdx.x * 256 + threadIdx.x;
    int lane = threadIdx.x & 63;
    int w = threadIdx.x >> 6;
    int v = (i < N) ? deg[i] : 0;
    int s = wave_incl_scan(v, lane);
    __shared__ int wsum[4];
    if (lane == 63) wsum[w] = s;
    __syncthreads();
    int off = 0;
    #pragma unroll
    for (int k = 0; k < 4; k++) if (k < w) off += wsum[k];
    s += off;
    if (i < N) incl[i] = s;
    if (threadIdx.x == 255) bsum[blockIdx.x] = s;
}

__global__ __launch_bounds__(256) void scan2_kernel(
    const int* __restrict__ bsum, int* __restrict__ bsx, int nb)
{
    int t = threadIdx.x;
    int lane = t & 63;
    int w = t >> 6;
    int v = (t < nb) ? bsum[t] : 0;
    int s = wave_incl_scan(v, lane);
    __shared__ int wsum[4];
    if (lane == 63) wsum[w] = s;
    __syncthreads();
    int off = 0;
    #pragma unroll
    for (int k = 0; k < 4; k++) if (k < w) off += wsum[k];
    s += off;
    if (t < nb) bsx[t] = s - v;   // exclusive
}

__global__ __launch_bounds__(256) void scan3_kernel(
    int* __restrict__ deg_cursor, int* __restrict__ incl_rowptr,
    const int* __restrict__ bsx, int N)
{
    int i = blockIdx.x * 256 + threadIdx.x;
    if (i >= N) return;
    int incl = incl_rowptr[i] + bsx[blockIdx.x];
    int d = deg_cursor[i];
    int excl = incl - d;
    incl_rowptr[i] = excl;        // row_ptr[i]
    deg_cursor[i] = excl;         // cursor[i]
    if (i == N - 1) incl_rowptr[N] = incl;
}

// ---------------- x fp32 -> bf16 table ----------------
__global__ __launch_bounds__(256) void xconv_kernel(
    const float* __restrict__ x, ushort* __restrict__ xb, int total4)
{
    int i = blockIdx.x * 256 + threadIdx.x;
    if (i >= total4) return;
    float4 v = ((const float4*)x)[i];
    ushort4 o;
    o.x = (ushort)bf16_rne(v.x); o.y = (ushort)bf16_rne(v.y);
    o.z = (ushort)bf16_rne(v.z); o.w = (ushort)bf16_rne(v.w);
    ((ushort4*)xb)[i] = o;
}

// ---------------- all W fp32 [K][128] -> bf16 [128][K] (transposed), one launch ----------------
__global__ __launch_bounds__(256) void wconv_all_kernel(
    const float* __restrict__ W1, const float* __restrict__ W2,
    const float* __restrict__ W3, const float* __restrict__ W4,
    ushort* __restrict__ w1t, ushort* __restrict__ w2t,
    ushort* __restrict__ w3t, ushort* __restrict__ w4t)
{
    int i = blockIdx.x * 256 + threadIdx.x;
    if (i < 8192) {                       // W1: 128 x 64
        int n = i >> 6, k = i & 63;
        w1t[i] = (ushort)bf16_rne(W1[(size_t)k * 128 + n]);
    } else if (i < 8192 + 16384) {
        int j = i - 8192; int n = j >> 7, k = j & 127;
        w2t[j] = (ushort)bf16_rne(W2[(size_t)k * 128 + n]);
    } else if (i < 8192 + 32768) {
        int j = i - 8192 - 16384; int n = j >> 7, k = j & 127;
        w3t[j] = (ushort)bf16_rne(W3[(size_t)k * 128 + n]);
    } else if (i < 8192 + 49152) {
        int j = i - 8192 - 32768; int n = j >> 7, k = j & 127;
        w4t[j] = (ushort)bf16_rne(W4[(size_t)k * 128 + n]);
    }
}

// ---------------- gather64: 2 neighbors/iter; row = 32 uints (64ch bf16) ----------------
__global__ __launch_bounds__(256) void gather64_kernel(
    const ushort* __restrict__ xb, const int* __restrict__ rp,
    const ushort* __restrict__ col, ushort* __restrict__ outb, int N)
{
    const unsigned* xu = (const unsigned*)xb;
    unsigned* outu = (unsigned*)outb;
    int wid = (blockIdx.x * blockDim.x + threadIdx.x) >> 6;
    int lane = threadIdx.x & 63;
    int half = lane >> 5, cl = lane & 31;
    if (wid >= N) return;
    int b = rp[wid], e2 = rp[wid + 1];
    unsigned us = xu[(size_t)wid * 32 + cl];
    float ax = (half == 0) ? lo_f(us) : 0.f;
    float ay = (half == 0) ? hi_f(us) : 0.f;
    for (int base = b; base < e2; base += 64) {
        int cnt = e2 - base; if (cnt > 64) cnt = 64;
        int myc = (base + lane < e2) ? (int)col[base + lane] : 0;
        for (int j = 0; j < cnt; j += 2) {
            int jj = j + half;                 // half 0: even, half 1: odd
            int s = __shfl(myc, jj);           // jj==cnt (odd tail) masked below
            unsigned u = xu[(size_t)s * 32 + cl];
            if (jj < cnt) { ax += lo_f(u); ay += hi_f(u); }
        }
    }
    ax += __shfl_xor(ax, 32);
    ay += __shfl_xor(ay, 32);
    if (half == 0) outu[(size_t)wid * 32 + cl] = bf16_rne(ax) | (bf16_rne(ay) << 16);
}

// ---------------- gather128: bf16 in/out, fp32 accum, 4x unrolled ----------------
__global__ __launch_bounds__(256) void gather128_kernel(
    const ushort* __restrict__ in, const int* __restrict__ rp,
    const ushort* __restrict__ col, ushort* __restrict__ outb, int N)
{
    const unsigned* inu = (const unsigned*)in;
    unsigned* outu = (unsigned*)outb;
    int wid = (blockIdx.x * blockDim.x + threadIdx.x) >> 6;
    int lane = threadIdx.x & 63;
    if (wid >= N) return;
    int b = rp[wid], e2 = rp[wid + 1];
    unsigned u0 = inu[(size_t)wid * 64 + lane];
    float ax = lo_f(u0), ay = hi_f(u0);
    float bx = 0.f, by = 0.f;
    for (int base = b; base < e2; base += 64) {
        int cnt = e2 - base; if (cnt > 64) cnt = 64;
        int myc = (base + lane < e2) ? (int)col[base + lane] : 0;
        int j = 0;
        for (; j + 3 < cnt; j += 4) {
            int s0 = __shfl(myc, j),     s1 = __shfl(myc, j + 1);
            int s2 = __shfl(myc, j + 2), s3 = __shfl(myc, j + 3);
            unsigned ua = inu[(size_t)s0 * 64 + lane];
            unsigned ub = inu[(size_t)s1 * 64 + lane];
            unsigned uc = inu[(size_t)s2 * 64 + lane];
            unsigned ud = inu[(size_t)s3 * 64 + lane];
            ax += lo_f(ua); ay += hi_f(ua);
            bx += lo_f(ub); by += hi_f(ub);
            ax += lo_f(uc); ay += hi_f(uc);
            bx += lo_f(ud); by += hi_f(ud);
        }
        for (; j < cnt; j++) {
            int s = __shfl(myc, j);
            unsigned u = inu[(size_t)s * 64 + lane];
            ax += lo_f(u); ay += hi_f(u);
        }
    }
    ax += bx; ay += by;
    outu[(size_t)wid * 64 + lane] = bf16_rne(ax) | (bf16_rne(ay) << 16);
}

// ---------------- fused MLP (+ optional output head) ----------------
// out = relu(relu(A@W1+b1)@W2+b2); HEAD: fout[n] = dot(out_row, Wout)+bout,
// and the bf16 row is NOT written. Block: 64 rows, 256 threads.
template<int K1, bool HEAD>
__global__ __launch_bounds__(256) void mlp_fused_kernel(
    const ushort* __restrict__ A, const ushort* __restrict__ W1t,
    const ushort* __restrict__ W2t, const float* __restrict__ b1,
    const float* __restrict__ b2, ushort* __restrict__ outb,
    const float* __restrict__ Wout, const float* __restrict__ bout,
    float* __restrict__ fout, int N)
{
    constexpr int SA = K1 + 8;                       // ushort stride (16B-mult)
    __shared__ __align__(16) ushort Asm[64 * SA];
    __shared__ __align__(16) ushort Wsm[128 * 136];  // W1 (stride SA) then W2 (stride 136)
    __shared__ __align__(16) ushort T1s[64 * 136];

    const int t  = threadIdx.x;
    const int n0 = blockIdx.x * 64;
    const int w  = t >> 6, l = t & 63;
    const int lr = l & 15, lg = l >> 4;

    // ---- stage A tile 64 x K1 (4 threads/row) ----
    {
        int row = t >> 2, seg = t & 3;
        int n = n0 + row; int nc = n < N ? n : N - 1;
        const uint4* src = (const uint4*)(A + (size_t)nc * K1 + seg * (K1 / 4));
        uint4* dst = (uint4*)&Asm[row * SA + seg * (K1 / 4)];
        #pragma unroll
        for (int q = 0; q < K1 / 32; q++) dst[q] = src[q];
    }
    // ---- stage W1t 128 x K1 (2 threads/row) ----
    {
        int n = t >> 1, half = t & 1;
        const uint4* src = (const uint4*)(W1t + (size_t)n * K1 + half * (K1 / 2));
        uint4* dst = (uint4*)&Wsm[n * SA + half * (K1 / 2)];
        #pragma unroll
        for (int q = 0; q < K1 / 16; q++) dst[q] = src[q];
    }
    __syncthreads();

    // ---- pass 1: t1 = relu(A @ W1 + b1) ----
    f32x4 acc[8];
    #pragma unroll
    for (int c = 0; c < 8; c++) acc[c] = (f32x4){0.f, 0.f, 0.f, 0.f};
    #pragma unroll
    for (int ks = 0; ks < K1 / 32; ks++) {
        short8 a = *(const short8*)&Asm[(w * 16 + lr) * SA + ks * 32 + lg * 8];
        #pragma unroll
        for (int c = 0; c < 8; c++) {
            short8 bb = *(const short8*)&Wsm[(c * 16 + lr) * SA + ks * 32 + lg * 8];
            acc[c] = __builtin_amdgcn_mfma_f32_16x16x32_bf16(a, bb, acc[c], 0, 0, 0);
        }
    }
    #pragma unroll
    for (int c = 0; c < 8; c++) {
        float bc = b1[c * 16 + lr];
        #pragma unroll
        for (int j = 0; j < 4; j++) {
            float v = fmaxf(acc[c][j] + bc, 0.f);
            T1s[(w * 16 + lg * 4 + j) * 136 + c * 16 + lr] = (ushort)bf16_rne(v);
        }
    }
    __syncthreads();   // T1 complete; Wsm pass-1 reads done

    // ---- stage W2t 128 x 128 over Wsm (stride 136) ----
    {
        int n = t >> 1, half = t & 1;
        const uint4* src = (const uint4*)(W2t + (size_t)n * 128 + half * 64);
        uint4* dst = (uint4*)&Wsm[n * 136 + half * 64];
        #pragma unroll
        for (int q = 0; q < 8; q++) dst[q] = src[q];
    }
    __syncthreads();

    // ---- pass 2: h = relu(t1 @ W2 + b2) ----
    #pragma unroll
    for (int c = 0; c < 8; c++) acc[c] = (f32x4){0.f, 0.f, 0.f, 0.f};
    #pragma unroll
    for (int ks = 0; ks < 4; ks++) {
        short8 a = *(const short8*)&T1s[(w * 16 + lr) * 136 + ks * 32 + lg * 8];
        #pragma unroll
        for (int c = 0; c < 8; c++) {
            short8 bb = *(const short8*)&Wsm[(c * 16 + lr) * 136 + ks * 32 + lg * 8];
            acc[c] = __builtin_amdgcn_mfma_f32_16x16x32_bf16(a, bb, acc[c], 0, 0, 0);
        }
    }
    if (HEAD) {
        // fout[n] = sum_ch relu(h)[ch] * Wout[ch] + bout; reduce over lr lanes
        float wv[8];
        #pragma unroll
        for (int c = 0; c < 8; c++) wv[c] = Wout[c * 16 + lr];
        float p[4] = {0.f, 0.f, 0.f, 0.f};
        #pragma unroll
        for (int c = 0; c < 8; c++) {
            float bc = b2[c * 16 + lr];
            #pragma unroll
            for (int j = 0; j < 4; j++) {
                float v = fmaxf(acc[c][j] + bc, 0.f);
                p[j] += v * wv[c];
            }
        }
        #pragma unroll
        for (int j = 0; j < 4; j++)
            #pragma unroll
            for (int off = 1; off < 16; off <<= 1) p[j] += __shfl_xor(p[j], off);
        if (lr == 0) {
            int row0 = n0 + w * 16 + lg * 4;
            float bo = bout[0];
            #pragma unroll
            for (int j = 0; j < 4; j++)
                if (row0 + j < N) fout[row0 + j] = p[j] + bo;
        }
    } else {
        #pragma unroll
        for (int c = 0; c < 8; c++) {
            float bc = b2[c * 16 + lr];
            #pragma unroll
            for (int j = 0; j < 4; j++) {
                int row = n0 + w * 16 + lg * 4 + j;
                if (row < N) {
                    float v = fmaxf(acc[c][j] + bc, 0.f);
                    outb[(size_t)row * 128 + c * 16 + lr] = (ushort)bf16_rne(v);
                }
            }
        }
    }
}

extern "C" void kernel_launch(void* const* d_in, const int* in_sizes, int n_in,
                              void* d_out, int out_size, void* d_ws, size_t ws_size,
                              hipStream_t stream) {
    const float* x    = (const float*)d_in[0];
    const void*  ei   = d_in[1];
    const float* W1   = (const float*)d_in[2];
    const float* b1   = (const float*)d_in[3];
    const float* W2   = (const float*)d_in[4];
    const float* b2   = (const float*)d_in[5];
    const float* W3   = (const float*)d_in[6];
    const float* b3   = (const float*)d_in[7];
    const float* W4   = (const float*)d_in[8];
    const float* b4   = (const float*)d_in[9];
    const float* Wout = (const float*)d_in[10];
    const float* bout = (const float*)d_in[11];
    float* out = (float*)d_out;

    const int E = in_sizes[1] / 2;
    const int N = N_NODES;
    const int nb = (N + 255) / 256;

    // ---- workspace layout (256B-aligned slots) ----
    char* wsb = (char*)d_ws;
    size_t off = 0;
    auto alloc = [&](size_t bytes) -> void* {
        void* p = wsb + off;
        off = (off + bytes + 255) & ~(size_t)255;
        return p;
    };
    int*    flag   = (int*)alloc(4);
    int*    deg    = (int*)alloc((size_t)N * 4);
    int*    rowptr = (int*)alloc((size_t)(N + 1) * 4);
    int*    bsum   = (int*)alloc(256 * 4);
    int*    bsx    = (int*)alloc(256 * 4);
    ushort* srcs16 = (ushort*)alloc((size_t)E * 2);
    ushort* dsts16 = (ushort*)alloc((size_t)E * 2);
    ushort* col    = (ushort*)alloc((size_t)E * 2);
    ushort* xb     = (ushort*)alloc((size_t)N * 64 * 2);
    ushort* w1t    = (ushort*)alloc(128 * 64 * 2);
    ushort* w2t    = (ushort*)alloc(128 * 128 * 2);
    ushort* w3t    = (ushort*)alloc(128 * 128 * 2);
    ushort* w4t    = (ushort*)alloc(128 * 128 * 2);
    ushort* agg1   = (ushort*)alloc((size_t)N * 64 * 2);
    ushort* h1     = (ushort*)alloc((size_t)N * 128 * 2);
    ushort* agg2   = (ushort*)alloc((size_t)N * 128 * 2);

    detect64_kernel<<<1, 256, 0, stream>>>((const int*)ei, flag);

    // ---- compact edges to ushort + build CSR (XCD-affine hist/fill) ----
    hipMemsetAsync(deg, 0, (size_t)N * sizeof(int), stream);
    compact_kernel<<<1024, 256, 0, stream>>>(ei, flag, srcs16, dsts16, E);
    hist8_kernel<<<2048, 256, 0, stream>>>(dsts16, deg, E, 256);
    scan1_kernel<<<nb, 256, 0, stream>>>(deg, rowptr, bsum, N);
    scan2_kernel<<<1, 256, 0, stream>>>(bsum, bsx, nb);
    scan3_kernel<<<nb, 256, 0, stream>>>(deg, rowptr, bsx, N);   // deg becomes cursor
    fill8_kernel<<<2048, 256, 0, stream>>>(srcs16, dsts16, deg, col, E, 256);

    // ---- convert inputs to bf16 ----
    xconv_kernel<<<(N * 64 / 4 + 255) / 256, 256, 0, stream>>>(x, xb, N * 64 / 4);
    wconv_all_kernel<<<(8192 + 49152 + 255) / 256, 256, 0, stream>>>(
        W1, W2, W3, W4, w1t, w2t, w3t, w4t);

    const int agg_blocks = (N * 64 + 255) / 256;   // wave per node
    const int mlp_blocks = (N + 63) / 64;          // 782

    // ---- layer 1 ----
    gather64_kernel<<<agg_blocks, 256, 0, stream>>>(xb, rowptr, col, agg1, N);
    mlp_fused_kernel<64, false><<<mlp_blocks, 256, 0, stream>>>(
        agg1, w1t, w2t, b1, b2, h1, nullptr, nullptr, nullptr, N);

    // ---- layer 2 (+ fused output head) ----
    gather128_kernel<<<agg_blocks, 256, 0, stream>>>(h1, rowptr, col, agg2, N);
    mlp_fused_kernel<128, true><<<mlp_blocks, 256, 0, stream>>>(
        agg2, w3t, w4t, b3, b4, nullptr, Wout, bout, out, N);
}

// Round 12
// 249.405 us; speedup vs baseline: 1.1020x; 1.1020x over previous
//
#include <hip/hip_runtime.h>

// GIN: 2x GINConv(eps=0, MLP 2-layer) + ReLU, then Linear(128->1).
// N=50000 nodes, E=800000 edges, IN=64, HID=128.
//
// Round 12: structural cuts.
// (a) launches 14 -> 10: detect+memset folded into compact; scan2 folded
//     into scan3 (per-block bsum prefix); xconv+wconv merged.
// (b) MLP LDS 69.6KB -> 52.2KB via T1s aliasing Asm (one extra barrier)
//     -> 3 blocks/CU instead of 2.
// (c) gather128: 8 loads in flight; gather64: 4 dual-row loads per iter.

#define N_NODES 50000
#define IN_CH 64
#define HID 128
#define REGION 6250   // N/8 dst-nodes per XCD-affine region

typedef short short8 __attribute__((ext_vector_type(8)));
typedef float f32x4 __attribute__((ext_vector_type(4)));

__device__ __forceinline__ unsigned bf16_rne(float f) {
    unsigned u = __float_as_uint(f);
    return (u + 0x7FFFu + ((u >> 16) & 1u)) >> 16;
}
__device__ __forceinline__ float lo_f(unsigned u) { return __uint_as_float(u << 16); }
__device__ __forceinline__ float hi_f(unsigned u) { return __uint_as_float(u & 0xFFFF0000u); }

// ---------------- compact edges to ushort (+ dtype detect, + zero deg) ----------------
// Each block independently detects int64 vs int32: if data is int64 (values
// < 2^31), every odd int32 word of the first 256 pairs is 0. Uniform result.
__global__ __launch_bounds__(256) void compact_kernel(
    const int* __restrict__ ei32, ushort* __restrict__ srcs,
    ushort* __restrict__ dsts, int* __restrict__ deg, int E, int N)
{
    int t = threadIdx.x;
    int v = ei32[2 * t + 1];
    unsigned long long b = __ballot(v != 0);
    __shared__ unsigned long long r[4];
    if ((t & 63) == 0) r[t >> 6] = b;
    __syncthreads();
    int is64 = ((r[0] | r[1] | r[2] | r[3]) == 0ULL) ? 1 : 0;

    // zero deg (histogram target)
    for (int i = blockIdx.x * 256 + t; i < N; i += gridDim.x * 256) deg[i] = 0;

    const long long* p64 = (const long long*)ei32;
    for (int e = blockIdx.x * 256 + t; e < E; e += gridDim.x * 256) {
        int s, d;
        if (is64) { s = (int)p64[e]; d = (int)p64[E + e]; }
        else      { s = ei32[e];     d = ei32[E + e]; }
        srcs[e] = (ushort)s;
        dsts[e] = (ushort)d;
    }
}

// ---------------- CSR build, XCD-affine (bid%8 == dst region), ushort ids ----------------
__global__ __launch_bounds__(256) void hist8_kernel(
    const ushort* __restrict__ dsts, int* __restrict__ deg, int E, int nsub)
{
    int g   = blockIdx.x & 7;
    int sub = blockIdx.x >> 3;
    int lo = g * REGION, hi = lo + REGION;
    for (int e = sub * 256 + threadIdx.x; e < E; e += nsub * 256) {
        int d = dsts[e];
        if (d >= lo && d < hi) atomicAdd(&deg[d], 1);
    }
}

__global__ __launch_bounds__(256) void fill8_kernel(
    const ushort* __restrict__ srcs, const ushort* __restrict__ dsts,
    int* __restrict__ cursor, ushort* __restrict__ col, int E, int nsub)
{
    int g   = blockIdx.x & 7;
    int sub = blockIdx.x >> 3;
    int lo = g * REGION, hi = lo + REGION;
    for (int e = sub * 256 + threadIdx.x; e < E; e += nsub * 256) {
        int d = dsts[e];
        if (d >= lo && d < hi) {
            int pos = atomicAdd(&cursor[d], 1);
            col[pos] = srcs[e];
        }
    }
}

__device__ __forceinline__ int wave_incl_scan(int v, int lane) {
    #pragma unroll
    for (int off = 1; off < 64; off <<= 1) {
        int u = __shfl_up(v, off);
        if (lane >= off) v += u;
    }
    return v;
}

__global__ __launch_bounds__(256) void scan1_kernel(
    const int* __restrict__ deg, int* __restrict__ incl,
    int* __restrict__ bsum, int N)
{
    int i = blockIdx.x * 256 + threadIdx.x;
    int lane = threadIdx.x & 63;
    int w = threadIdx.x >> 6;
    int v = (i < N) ? deg[i] : 0;
    int s = wave_incl_scan(v, lane);
    __shared__ int wsum[4];
    if (lane == 63) wsum[w] = s;
    __syncthreads();
    int off = 0;
    #pragma unroll
    for (int k = 0; k < 4; k++) if (k < w) off += wsum[k];
    s += off;
    if (i < N) incl[i] = s;
    if (threadIdx.x == 255) bsum[blockIdx.x] = s;
}

// scan3b: finalize row_ptr/cursor; each block computes its own bsum prefix.
__global__ __launch_bounds__(256) void scan3b_kernel(
    int* __restrict__ deg_cursor, int* __restrict__ incl_rowptr,
    const int* __restrict__ bsum, int N, int nb)
{
    int t = threadIdx.x;
    int lane = t & 63;
    int w = t >> 6;
    // prefix = sum of bsum[0..bid-1]
    int v = (t < nb && t < blockIdx.x) ? bsum[t] : 0;
    #pragma unroll
    for (int off = 32; off; off >>= 1) v += __shfl_down(v, off);
    __shared__ int ws[4];
    if (lane == 0) ws[w] = v;
    __syncthreads();
    int pref = ws[0] + ws[1] + ws[2] + ws[3];

    int i = blockIdx.x * 256 + t;
    if (i >= N) return;
    int incl = incl_rowptr[i] + pref;
    int d = deg_cursor[i];
    int excl = incl - d;
    incl_rowptr[i] = excl;        // row_ptr[i]
    deg_cursor[i] = excl;         // cursor[i]
    if (i == N - 1) incl_rowptr[N] = incl;
}

// ---------------- conversions: x -> bf16 table, all W -> bf16 transposed ----------------
#define XITEMS (N_NODES * IN_CH / 4)   // 800000 float4 items
__global__ __launch_bounds__(256) void conv_all_kernel(
    const float* __restrict__ x,
    const float* __restrict__ W1, const float* __restrict__ W2,
    const float* __restrict__ W3, const float* __restrict__ W4,
    ushort* __restrict__ xb,
    ushort* __restrict__ w1t, ushort* __restrict__ w2t,
    ushort* __restrict__ w3t, ushort* __restrict__ w4t)
{
    int i = blockIdx.x * 256 + threadIdx.x;
    if (i < XITEMS) {
        float4 v = ((const float4*)x)[i];
        ushort4 o;
        o.x = (ushort)bf16_rne(v.x); o.y = (ushort)bf16_rne(v.y);
        o.z = (ushort)bf16_rne(v.z); o.w = (ushort)bf16_rne(v.w);
        ((ushort4*)xb)[i] = o;
        return;
    }
    int j = i - XITEMS;
    if (j < 8192) {                       // W1: 128 x 64
        int n = j >> 6, k = j & 63;
        w1t[j] = (ushort)bf16_rne(W1[(size_t)k * 128 + n]);
    } else if (j < 8192 + 16384) {
        int q = j - 8192; int n = q >> 7, k = q & 127;
        w2t[q] = (ushort)bf16_rne(W2[(size_t)k * 128 + n]);
    } else if (j < 8192 + 32768) {
        int q = j - 8192 - 16384; int n = q >> 7, k = q & 127;
        w3t[q] = (ushort)bf16_rne(W3[(size_t)k * 128 + n]);
    } else if (j < 8192 + 49152) {
        int q = j - 8192 - 32768; int n = q >> 7, k = q & 127;
        w4t[q] = (ushort)bf16_rne(W4[(size_t)k * 128 + n]);
    }
}

// ---------------- gather64: 8 neighbors/iter (4 dual-row loads in flight) ----------------
__global__ __launch_bounds__(256) void gather64_kernel(
    const ushort* __restrict__ xb, const int* __restrict__ rp,
    const ushort* __restrict__ col, ushort* __restrict__ outb, int N)
{
    const unsigned* xu = (const unsigned*)xb;
    unsigned* outu = (unsigned*)outb;
    int wid = (blockIdx.x * blockDim.x + threadIdx.x) >> 6;
    int lane = threadIdx.x & 63;
    int half = lane >> 5, cl = lane & 31;
    if (wid >= N) return;
    int b = rp[wid], e2 = rp[wid + 1];
    unsigned us = xu[(size_t)wid * 32 + cl];
    float ax = (half == 0) ? lo_f(us) : 0.f;
    float ay = (half == 0) ? hi_f(us) : 0.f;
    for (int base = b; base < e2; base += 64) {
        int cnt = e2 - base; if (cnt > 64) cnt = 64;
        int myc = (base + lane < e2) ? (int)col[base + lane] : 0;
        int j = 0;
        for (; j + 7 < cnt; j += 8) {      // 4 dual-loads, all lanes valid
            int s0 = __shfl(myc, j +     half);
            int s1 = __shfl(myc, j + 2 + half);
            int s2 = __shfl(myc, j + 4 + half);
            int s3 = __shfl(myc, j + 6 + half);
            unsigned u0 = xu[(size_t)s0 * 32 + cl];
            unsigned u1 = xu[(size_t)s1 * 32 + cl];
            unsigned u2 = xu[(size_t)s2 * 32 + cl];
            unsigned u3 = xu[(size_t)s3 * 32 + cl];
            ax += lo_f(u0); ay += hi_f(u0);
            ax += lo_f(u1); ay += hi_f(u1);
            ax += lo_f(u2); ay += hi_f(u2);
            ax += lo_f(u3); ay += hi_f(u3);
        }
        for (; j < cnt; j += 2) {          // masked tail
            int jj = j + half;
            int s = __shfl(myc, jj);
            unsigned u = xu[(size_t)s * 32 + cl];
            if (jj < cnt) { ax += lo_f(u); ay += hi_f(u); }
        }
    }
    ax += __shfl_xor(ax, 32);
    ay += __shfl_xor(ay, 32);
    if (half == 0) outu[(size_t)wid * 32 + cl] = bf16_rne(ax) | (bf16_rne(ay) << 16);
}

// ---------------- gather128: bf16 in/out, fp32 accum, 8 loads in flight ----------------
__global__ __launch_bounds__(256) void gather128_kernel(
    const ushort* __restrict__ in, const int* __restrict__ rp,
    const ushort* __restrict__ col, ushort* __restrict__ outb, int N)
{
    const unsigned* inu = (const unsigned*)in;
    unsigned* outu = (unsigned*)outb;
    int wid = (blockIdx.x * blockDim.x + threadIdx.x) >> 6;
    int lane = threadIdx.x & 63;
    if (wid >= N) return;
    int b = rp[wid], e2 = rp[wid + 1];
    unsigned u0 = inu[(size_t)wid * 64 + lane];
    float ax = lo_f(u0), ay = hi_f(u0);
    float bx = 0.f, by = 0.f;
    for (int base = b; base < e2; base += 64) {
        int cnt = e2 - base; if (cnt > 64) cnt = 64;
        int myc = (base + lane < e2) ? (int)col[base + lane] : 0;
        int j = 0;
        for (; j + 7 < cnt; j += 8) {
            int s0 = __shfl(myc, j),     s1 = __shfl(myc, j + 1);
            int s2 = __shfl(myc, j + 2), s3 = __shfl(myc, j + 3);
            int s4 = __shfl(myc, j + 4), s5 = __shfl(myc, j + 5);
            int s6 = __shfl(myc, j + 6), s7 = __shfl(myc, j + 7);
            unsigned va = inu[(size_t)s0 * 64 + lane];
            unsigned vb = inu[(size_t)s1 * 64 + lane];
            unsigned vc = inu[(size_t)s2 * 64 + lane];
            unsigned vd = inu[(size_t)s3 * 64 + lane];
            unsigned ve = inu[(size_t)s4 * 64 + lane];
            unsigned vf = inu[(size_t)s5 * 64 + lane];
            unsigned vg = inu[(size_t)s6 * 64 + lane];
            unsigned vh = inu[(size_t)s7 * 64 + lane];
            ax += lo_f(va); ay += hi_f(va);
            bx += lo_f(vb); by += hi_f(vb);
            ax += lo_f(vc); ay += hi_f(vc);
            bx += lo_f(vd); by += hi_f(vd);
            ax += lo_f(ve); ay += hi_f(ve);
            bx += lo_f(vf); by += hi_f(vf);
            ax += lo_f(vg); ay += hi_f(vg);
            bx += lo_f(vh); by += hi_f(vh);
        }
        for (; j < cnt; j++) {
            int s = __shfl(myc, j);
            unsigned u = inu[(size_t)s * 64 + lane];
            ax += lo_f(u); ay += hi_f(u);
        }
    }
    ax += bx; ay += by;
    outu[(size_t)wid * 64 + lane] = bf16_rne(ax) | (bf16_rne(ay) << 16);
}

// ---------------- fused MLP (+ optional output head), LDS-aliased ----------------
// out = relu(relu(A@W1+b1)@W2+b2). LDS: [64 rows | 128 rows] x 136 ushorts.
// T1s aliases Asm (dead after pass-1 reads; extra barrier covers the WAR).
// 52224 B -> 3 blocks/CU.
template<int K1, bool HEAD>
__global__ __launch_bounds__(256) void mlp_fused_kernel(
    const ushort* __restrict__ A, const ushort* __restrict__ W1t,
    const ushort* __restrict__ W2t, const float* __restrict__ b1,
    const float* __restrict__ b2, ushort* __restrict__ outb,
    const float* __restrict__ Wout, const float* __restrict__ bout,
    float* __restrict__ fout, int N)
{
    constexpr int SA = K1 + 8;                        // pass-1 ushort stride
    __shared__ __align__(16) ushort lds[(64 + 128) * 136];
    ushort* Asm = lds;                                // stride SA, 64 rows
    ushort* T1s = lds;                                // stride 136, aliases Asm
    ushort* Wsm = lds + 64 * 136;                     // W1 stride SA, W2 stride 136

    const int t  = threadIdx.x;
    const int n0 = blockIdx.x * 64;
    const int w  = t >> 6, l = t & 63;
    const int lr = l & 15, lg = l >> 4;

    // ---- stage A tile 64 x K1 (4 threads/row) ----
    {
        int row = t >> 2, seg = t & 3;
        int n = n0 + row; int nc = n < N ? n : N - 1;
        const uint4* src = (const uint4*)(A + (size_t)nc * K1 + seg * (K1 / 4));
        uint4* dst = (uint4*)&Asm[row * SA + seg * (K1 / 4)];
        #pragma unroll
        for (int q = 0; q < K1 / 32; q++) dst[q] = src[q];
    }
    // ---- stage W1t 128 x K1 (2 threads/row) ----
    {
        int n = t >> 1, half = t & 1;
        const uint4* src = (const uint4*)(W1t + (size_t)n * K1 + half * (K1 / 2));
        uint4* dst = (uint4*)&Wsm[n * SA + half * (K1 / 2)];
        #pragma unroll
        for (int q = 0; q < K1 / 16; q++) dst[q] = src[q];
    }
    __syncthreads();

    // ---- pass 1: t1 = relu(A @ W1 + b1) ----
    f32x4 acc[8];
    #pragma unroll
    for (int c = 0; c < 8; c++) acc[c] = (f32x4){0.f, 0.f, 0.f, 0.f};
    #pragma unroll
    for (int ks = 0; ks < K1 / 32; ks++) {
        short8 a = *(const short8*)&Asm[(w * 16 + lr) * SA + ks * 32 + lg * 8];
        #pragma unroll
        for (int c = 0; c < 8; c++) {
            short8 bb = *(const short8*)&Wsm[(c * 16 + lr) * SA + ks * 32 + lg * 8];
            acc[c] = __builtin_amdgcn_mfma_f32_16x16x32_bf16(a, bb, acc[c], 0, 0, 0);
        }
    }
    __syncthreads();   // all pass-1 LDS reads done (Asm + W1) before overwrite

    // ---- T1 store (over Asm region) + stage W2t (over W1 region) ----
    #pragma unroll
    for (int c = 0; c < 8; c++) {
        float bc = b1[c * 16 + lr];
        #pragma unroll
        for (int j = 0; j < 4; j++) {
            float v = fmaxf(acc[c][j] + bc, 0.f);
            T1s[(w * 16 + lg * 4 + j) * 136 + c * 16 + lr] = (ushort)bf16_rne(v);
        }
    }
    {
        int n = t >> 1, half = t & 1;
        const uint4* src = (const uint4*)(W2t + (size_t)n * 128 + half * 64);
        uint4* dst = (uint4*)&Wsm[n * 136 + half * 64];
        #pragma unroll
        for (int q = 0; q < 8; q++) dst[q] = src[q];
    }
    __syncthreads();

    // ---- pass 2: h = relu(t1 @ W2 + b2) ----
    #pragma unroll
    for (int c = 0; c < 8; c++) acc[c] = (f32x4){0.f, 0.f, 0.f, 0.f};
    #pragma unroll
    for (int ks = 0; ks < 4; ks++) {
        short8 a = *(const short8*)&T1s[(w * 16 + lr) * 136 + ks * 32 + lg * 8];
        #pragma unroll
        for (int c = 0; c < 8; c++) {
            short8 bb = *(const short8*)&Wsm[(c * 16 + lr) * 136 + ks * 32 + lg * 8];
            acc[c] = __builtin_amdgcn_mfma_f32_16x16x32_bf16(a, bb, acc[c], 0, 0, 0);
        }
    }
    if (HEAD) {
        float wv[8];
        #pragma unroll
        for (int c = 0; c < 8; c++) wv[c] = Wout[c * 16 + lr];
        float p[4] = {0.f, 0.f, 0.f, 0.f};
        #pragma unroll
        for (int c = 0; c < 8; c++) {
            float bc = b2[c * 16 + lr];
            #pragma unroll
            for (int j = 0; j < 4; j++) {
                float v = fmaxf(acc[c][j] + bc, 0.f);
                p[j] += v * wv[c];
            }
        }
        #pragma unroll
        for (int j = 0; j < 4; j++)
            #pragma unroll
            for (int off = 1; off < 16; off <<= 1) p[j] += __shfl_xor(p[j], off);
        if (lr == 0) {
            int row0 = n0 + w * 16 + lg * 4;
            float bo = bout[0];
            #pragma unroll
            for (int j = 0; j < 4; j++)
                if (row0 + j < N) fout[row0 + j] = p[j] + bo;
        }
    } else {
        #pragma unroll
        for (int c = 0; c < 8; c++) {
            float bc = b2[c * 16 + lr];
            #pragma unroll
            for (int j = 0; j < 4; j++) {
                int row = n0 + w * 16 + lg * 4 + j;
                if (row < N) {
                    float v = fmaxf(acc[c][j] + bc, 0.f);
                    outb[(size_t)row * 128 + c * 16 + lr] = (ushort)bf16_rne(v);
                }
            }
        }
    }
}

extern "C" void kernel_launch(void* const* d_in, const int* in_sizes, int n_in,
                              void* d_out, int out_size, void* d_ws, size_t ws_size,
                              hipStream_t stream) {
    const float* x    = (const float*)d_in[0];
    const int*   ei   = (const int*)d_in[1];
    const float* W1   = (const float*)d_in[2];
    const float* b1   = (const float*)d_in[3];
    const float* W2   = (const float*)d_in[4];
    const float* b2   = (const float*)d_in[5];
    const float* W3   = (const float*)d_in[6];
    const float* b3   = (const float*)d_in[7];
    const float* W4   = (const float*)d_in[8];
    const float* b4   = (const float*)d_in[9];
    const float* Wout = (const float*)d_in[10];
    const float* bout = (const float*)d_in[11];
    float* out = (float*)d_out;

    const int E = in_sizes[1] / 2;
    const int N = N_NODES;
    const int nb = (N + 255) / 256;   // 196

    // ---- workspace layout (256B-aligned slots) ----
    char* wsb = (char*)d_ws;
    size_t off = 0;
    auto alloc = [&](size_t bytes) -> void* {
        void* p = wsb + off;
        off = (off + bytes + 255) & ~(size_t)255;
        return p;
    };
    int*    deg    = (int*)alloc((size_t)N * 4);
    int*    rowptr = (int*)alloc((size_t)(N + 1) * 4);
    int*    bsum   = (int*)alloc(256 * 4);
    ushort* srcs16 = (ushort*)alloc((size_t)E * 2);
    ushort* dsts16 = (ushort*)alloc((size_t)E * 2);
    ushort* col    = (ushort*)alloc((size_t)E * 2);
    ushort* xb     = (ushort*)alloc((size_t)N * 64 * 2);
    ushort* w1t    = (ushort*)alloc(128 * 64 * 2);
    ushort* w2t    = (ushort*)alloc(128 * 128 * 2);
    ushort* w3t    = (ushort*)alloc(128 * 128 * 2);
    ushort* w4t    = (ushort*)alloc(128 * 128 * 2);
    ushort* agg1   = (ushort*)alloc((size_t)N * 64 * 2);
    ushort* h1     = (ushort*)alloc((size_t)N * 128 * 2);
    ushort* agg2   = (ushort*)alloc((size_t)N * 128 * 2);

    // ---- CSR build (compact w/ detect + zero-deg, XCD-affine hist/fill) ----
    compact_kernel<<<1024, 256, 0, stream>>>(ei, srcs16, dsts16, deg, E, N);
    hist8_kernel<<<2048, 256, 0, stream>>>(dsts16, deg, E, 256);
    scan1_kernel<<<nb, 256, 0, stream>>>(deg, rowptr, bsum, N);
    scan3b_kernel<<<nb, 256, 0, stream>>>(deg, rowptr, bsum, N, nb);  // deg -> cursor
    fill8_kernel<<<2048, 256, 0, stream>>>(srcs16, dsts16, deg, col, E, 256);

    // ---- conversions (x + all W in one launch) ----
    conv_all_kernel<<<(XITEMS + 57344 + 255) / 256, 256, 0, stream>>>(
        x, W1, W2, W3, W4, xb, w1t, w2t, w3t, w4t);

    const int agg_blocks = (N * 64 + 255) / 256;   // wave per node
    const int mlp_blocks = (N + 63) / 64;          // 782

    // ---- layer 1 ----
    gather64_kernel<<<agg_blocks, 256, 0, stream>>>(xb, rowptr, col, agg1, N);
    mlp_fused_kernel<64, false><<<mlp_blocks, 256, 0, stream>>>(
        agg1, w1t, w2t, b1, b2, h1, nullptr, nullptr, nullptr, N);

    // ---- layer 2 (+ fused output head) ----
    gather128_kernel<<<agg_blocks, 256, 0, stream>>>(h1, rowptr, col, agg2, N);
    mlp_fused_kernel<128, true><<<mlp_blocks, 256, 0, stream>>>(
        agg2, w3t, w4t, b3, b4, nullptr, Wout, bout, out, N);
}